// Round 2
// baseline (1323.014 us; speedup 1.0000x reference)
//
#include <hip/hip_runtime.h>
#include <hip/hip_bf16.h>

// LightGCN forward: 3 propagation layers + layer mean.
// CSR (by dst) built per call, then gather-based aggregation.
// Key trick: propagate y = rd .* x so the inner gather needs NO per-edge
// norm lookup:  x_next[i] = rd[i] * sum y[src],  y_next[i] = rd[i] * x_next[i].
// Layer kernel: 8-lane group per node, lane = feature quad (float4).

#define D 32

__global__ void deg_kernel(const int* __restrict__ dst, int E, int* __restrict__ deg) {
    int e = blockIdx.x * blockDim.x + threadIdx.x;
    if (e < E) atomicAdd(&deg[__builtin_nontemporal_load(&dst[e])], 1);
}

// --- exclusive scan over deg[0..n) -> row_ptr (+next copy), rd = rsqrt(deg) ---
__global__ void scan_sum_kernel(const int* __restrict__ deg, int n, int* __restrict__ partials) {
    int idx = blockIdx.x * 1024 + threadIdx.x;
    int v = (idx < n) ? deg[idx] : 0;
    for (int o = 32; o > 0; o >>= 1) v += __shfl_down(v, o, 64);
    __shared__ int sm[16];
    int wave = threadIdx.x >> 6;
    int lane = threadIdx.x & 63;
    if (lane == 0) sm[wave] = v;
    __syncthreads();
    if (threadIdx.x < 16) {
        int s = sm[threadIdx.x];
        for (int o = 8; o > 0; o >>= 1) s += __shfl_down(s, o, 16);
        if (threadIdx.x == 0) partials[blockIdx.x] = s;
    }
}

__global__ void scan_partials_kernel(int* __restrict__ partials, int nblk) {
    __shared__ int sm[1024];
    int t = threadIdx.x;
    int v = (t < nblk) ? partials[t] : 0;
    sm[t] = v;
    __syncthreads();
    for (int o = 1; o < 1024; o <<= 1) {
        int add = (t >= o) ? sm[t - o] : 0;
        __syncthreads();
        sm[t] += add;
        __syncthreads();
    }
    if (t < nblk) partials[t] = sm[t] - v;  // exclusive
}

__global__ void scan_write_kernel(const int* __restrict__ deg, int n, int E,
                                  const int* __restrict__ partials,
                                  int* __restrict__ row_ptr, int* __restrict__ next,
                                  float* __restrict__ rd) {
    __shared__ int sm[1024];
    int t = threadIdx.x;
    int idx = blockIdx.x * 1024 + t;
    int v = (idx < n) ? deg[idx] : 0;
    sm[t] = v;
    __syncthreads();
    for (int o = 1; o < 1024; o <<= 1) {
        int add = (t >= o) ? sm[t - o] : 0;
        __syncthreads();
        sm[t] += add;
        __syncthreads();
    }
    if (idx < n) {
        int excl = sm[t] - v + partials[blockIdx.x];
        row_ptr[idx] = excl;
        next[idx] = excl;
        rd[idx] = (v > 0) ? rsqrtf((float)v) : 0.0f;
    }
    if (idx == 0) row_ptr[n] = E;
}

__global__ void fill_kernel(const int* __restrict__ src, const int* __restrict__ dst, int E,
                            int* __restrict__ next, int* __restrict__ col) {
    int e = blockIdx.x * blockDim.x + threadIdx.x;
    if (e < E) {
        int dd = __builtin_nontemporal_load(&dst[e]);
        int ss = __builtin_nontemporal_load(&src[e]);
        int pos = atomicAdd(&next[dd], 1);
        __builtin_nontemporal_store(ss, &col[pos]);
    }
}

__global__ void init_kernel(const float* __restrict__ ue, const float* __restrict__ ie,
                            const float* __restrict__ rd, int nu32, int tot32,
                            float* __restrict__ y, float* __restrict__ acc) {
    int i = blockIdx.x * blockDim.x + threadIdx.x;
    if (i < tot32) {
        float v = (i < nu32) ? ue[i] : ie[i - nu32];
        acc[i] = 0.25f * v;        // layer-0 term, pre-scaled by 1/(L+1)
        y[i] = rd[i >> 5] * v;     // y0 = rd .* x0   (D == 32)
    }
}

// 8-lane group per node; lane holds feature quad q (float4).
// S_i = sum_{e in row i} y[col[e]];  x_next = rd[i]*S;  y_next = rd[i]*x_next.
__global__ void layer_kernel(const int* __restrict__ row_ptr, const int* __restrict__ col,
                             const float* __restrict__ rd, const float* __restrict__ yin,
                             float* __restrict__ yout, float* __restrict__ acc, int n) {
    int gid = blockIdx.x * blockDim.x + threadIdx.x;
    int node = gid >> 3;
    int q = gid & 7;
    if (node >= n) return;
    int e0 = row_ptr[node];
    int e1 = row_ptr[node + 1];
    float4 s = make_float4(0.f, 0.f, 0.f, 0.f);
    for (int base = e0; base < e1; base += 8) {
        int idx = base + q;
        int c = (idx < e1) ? __builtin_nontemporal_load(&col[idx]) : 0;
        int cnt = min(8, e1 - base);
        for (int j = 0; j < cnt; ++j) {
            int cj = __shfl(c, j, 8);
            const float4 v = *reinterpret_cast<const float4*>(yin + cj * D + q * 4);
            s.x += v.x; s.y += v.y; s.z += v.z; s.w += v.w;
        }
    }
    float r = rd[node];
    float4 xv = make_float4(r * s.x, r * s.y, r * s.z, r * s.w);

    float4* accp = reinterpret_cast<float4*>(acc + node * D + q * 4);
    float4 a = *accp;
    a.x += 0.25f * xv.x; a.y += 0.25f * xv.y; a.z += 0.25f * xv.z; a.w += 0.25f * xv.w;
    *accp = a;

    float4 yv = make_float4(r * xv.x, r * xv.y, r * xv.z, r * xv.w);
    *reinterpret_cast<float4*>(yout + node * D + q * 4) = yv;
}

extern "C" void kernel_launch(void* const* d_in, const int* in_sizes, int n_in,
                              void* d_out, int out_size, void* d_ws, size_t ws_size,
                              hipStream_t stream) {
    const int*   edge = (const int*)d_in[0];
    const float* ue   = (const float*)d_in[3];
    const float* ie   = (const float*)d_in[4];
    int E  = in_sizes[0] / 2;
    int nu = in_sizes[3] / D;
    int ni = in_sizes[4] / D;
    int n  = nu + ni;
    const int* src = edge;
    const int* dst = edge + E;
    float* out = (float*)d_out;

    // workspace layout (~102 MB)
    char* p = (char*)d_ws;
    int*   deg      = (int*)p;   p += (size_t)n * 4;
    int*   next     = (int*)p;   p += (size_t)n * 4;
    int*   row_ptr  = (int*)p;   p += (size_t)(n + 1) * 4;
    int*   partials = (int*)p;   p += 4096 * 4;
    float* rd       = (float*)p; p += (size_t)n * 4;
    int*   col      = (int*)p;   p += (size_t)E * 4;
    float* ya       = (float*)p; p += (size_t)n * D * 4;
    float* yb       = (float*)p; p += (size_t)n * D * 4;

    hipMemsetAsync(deg, 0, (size_t)n * 4, stream);

    deg_kernel<<<(E + 255) / 256, 256, 0, stream>>>(dst, E, deg);

    int nblk = (n + 1023) / 1024;   // 293 for n=300k (<= 1024 required)
    scan_sum_kernel<<<nblk, 1024, 0, stream>>>(deg, n, partials);
    scan_partials_kernel<<<1, 1024, 0, stream>>>(partials, nblk);
    scan_write_kernel<<<nblk, 1024, 0, stream>>>(deg, n, E, partials, row_ptr, next, rd);

    fill_kernel<<<(E + 255) / 256, 256, 0, stream>>>(src, dst, E, next, col);

    int tot32 = n * D;
    init_kernel<<<(tot32 + 255) / 256, 256, 0, stream>>>(ue, ie, rd, nu * D, tot32, ya, out);

    float* yin = ya;
    float* yout = yb;
    int tot8 = n * 8;
    for (int l = 0; l < 3; ++l) {
        layer_kernel<<<(tot8 + 255) / 256, 256, 0, stream>>>(row_ptr, col, rd, yin, yout, out, n);
        float* t = yin; yin = yout; yout = t;
    }
}

// Round 5
// 1122.489 us; speedup vs baseline: 1.1786x; 1.1786x over previous
//
#include <hip/hip_runtime.h>
#include <hip/hip_bf16.h>

// LightGCN forward: 3 propagation layers + layer mean.
// CSR (by dst) built per call, then gather-based aggregation.
// y = rd .* x is propagated so the inner gather needs no per-edge norm lookup.
// Fill uses dst-range ownership keyed on (blockIdx & 7): with round-robin
// block->XCD dispatch each col region is written by one XCD's L2, so 64B
// lines fully assemble before eviction (kills 16x write amplification).
// Correct regardless of actual dispatch mapping (coverage is by residue class).

#define D 32
#define FILL_CHUNK 2048

__global__ void deg_kernel(const int* __restrict__ dst, int E, int* __restrict__ deg) {
    int e = blockIdx.x * blockDim.x + threadIdx.x;
    if (e < E) atomicAdd(&deg[dst[e]], 1);
}

// --- exclusive scan over deg[0..n) -> row_ptr (+next copy), rd = rsqrt(deg) ---
__global__ void scan_sum_kernel(const int* __restrict__ deg, int n, int* __restrict__ partials) {
    int idx = blockIdx.x * 1024 + threadIdx.x;
    int v = (idx < n) ? deg[idx] : 0;
    for (int o = 32; o > 0; o >>= 1) v += __shfl_down(v, o, 64);
    __shared__ int sm[16];
    int wave = threadIdx.x >> 6;
    int lane = threadIdx.x & 63;
    if (lane == 0) sm[wave] = v;
    __syncthreads();
    if (threadIdx.x < 16) {
        int s = sm[threadIdx.x];
        for (int o = 8; o > 0; o >>= 1) s += __shfl_down(s, o, 16);
        if (threadIdx.x == 0) partials[blockIdx.x] = s;
    }
}

__global__ void scan_partials_kernel(int* __restrict__ partials, int nblk) {
    __shared__ int sm[1024];
    int t = threadIdx.x;
    int v = (t < nblk) ? partials[t] : 0;
    sm[t] = v;
    __syncthreads();
    for (int o = 1; o < 1024; o <<= 1) {
        int add = (t >= o) ? sm[t - o] : 0;
        __syncthreads();
        sm[t] += add;
        __syncthreads();
    }
    if (t < nblk) partials[t] = sm[t] - v;  // exclusive
}

__global__ void scan_write_kernel(const int* __restrict__ deg, int n, int E,
                                  const int* __restrict__ partials,
                                  int* __restrict__ row_ptr, int* __restrict__ next,
                                  float* __restrict__ rd) {
    __shared__ int sm[1024];
    int t = threadIdx.x;
    int idx = blockIdx.x * 1024 + t;
    int v = (idx < n) ? deg[idx] : 0;
    sm[t] = v;
    __syncthreads();
    for (int o = 1; o < 1024; o <<= 1) {
        int add = (t >= o) ? sm[t - o] : 0;
        __syncthreads();
        sm[t] += add;
        __syncthreads();
    }
    if (idx < n) {
        int excl = sm[t] - v + partials[blockIdx.x];
        row_ptr[idx] = excl;
        next[idx] = excl;
        rd[idx] = (v > 0) ? rsqrtf((float)v) : 0.0f;
    }
    if (idx == 0) row_ptr[n] = E;
}

// dst-range-ownership fill: group g = blockIdx&7 handles dst in [g*span,(g+1)*span).
// Each group scans the whole edge list in static chunked stride; edge list is
// L3-resident so the 8x re-read is cheap. col writes are localized per group.
__global__ void fill_kernel(const int* __restrict__ src, const int* __restrict__ dst,
                            int E, int span, int n,
                            int* __restrict__ next, int* __restrict__ col) {
    int own  = blockIdx.x & 7;
    int rank = blockIdx.x >> 3;
    int G    = gridDim.x >> 3;
    int lo = own * span;
    int hi = min(n, lo + span);
    for (int c = rank; (long)c * FILL_CHUNK < E; c += G) {
        int base = c * FILL_CHUNK;
        int end  = min(E, base + FILL_CHUNK);
        for (int i = base + (int)threadIdx.x; i < end; i += blockDim.x) {
            int d = dst[i];
            if (d >= lo && d < hi) {
                int pos = atomicAdd(&next[d], 1);
                col[pos] = src[i];
            }
        }
    }
}

__global__ void init_kernel(const float* __restrict__ ue, const float* __restrict__ ie,
                            const float* __restrict__ rd, int nu32, int tot32,
                            float* __restrict__ y, float* __restrict__ acc) {
    int i = blockIdx.x * blockDim.x + threadIdx.x;
    if (i < tot32) {
        float v = (i < nu32) ? ue[i] : ie[i - nu32];
        acc[i] = 0.25f * v;        // layer-0 term, pre-scaled by 1/(L+1)
        y[i] = rd[i >> 5] * v;     // y0 = rd .* x0   (D == 32)
    }
}

// 8-lane group per node; lane holds feature quad q (float4).
// S_i = sum_{e in row i} y[col[e]];  x_next = rd[i]*S;  y_next = rd[i]*x_next.
__global__ void layer_kernel(const int* __restrict__ row_ptr, const int* __restrict__ col,
                             const float* __restrict__ rd, const float* __restrict__ yin,
                             float* __restrict__ yout, float* __restrict__ acc, int n) {
    int gid = blockIdx.x * blockDim.x + threadIdx.x;
    int node = gid >> 3;
    int q = gid & 7;
    if (node >= n) return;
    int e0 = row_ptr[node];
    int e1 = row_ptr[node + 1];
    float4 s = make_float4(0.f, 0.f, 0.f, 0.f);
    for (int base = e0; base < e1; base += 8) {
        int idx = base + q;
        int c = (idx < e1) ? col[idx] : 0;
        int cnt = min(8, e1 - base);
        for (int j = 0; j < cnt; ++j) {
            int cj = __shfl(c, j, 8);
            const float4 v = *reinterpret_cast<const float4*>(yin + cj * D + q * 4);
            s.x += v.x; s.y += v.y; s.z += v.z; s.w += v.w;
        }
    }
    float r = rd[node];
    float4 xv = make_float4(r * s.x, r * s.y, r * s.z, r * s.w);

    float4* accp = reinterpret_cast<float4*>(acc + node * D + q * 4);
    float4 a = *accp;
    a.x += 0.25f * xv.x; a.y += 0.25f * xv.y; a.z += 0.25f * xv.z; a.w += 0.25f * xv.w;
    *accp = a;

    float4 yv = make_float4(r * xv.x, r * xv.y, r * xv.z, r * xv.w);
    *reinterpret_cast<float4*>(yout + node * D + q * 4) = yv;
}

extern "C" void kernel_launch(void* const* d_in, const int* in_sizes, int n_in,
                              void* d_out, int out_size, void* d_ws, size_t ws_size,
                              hipStream_t stream) {
    const int*   edge = (const int*)d_in[0];
    const float* ue   = (const float*)d_in[3];
    const float* ie   = (const float*)d_in[4];
    int E  = in_sizes[0] / 2;
    int nu = in_sizes[3] / D;
    int ni = in_sizes[4] / D;
    int n  = nu + ni;
    const int* src = edge;
    const int* dst = edge + E;
    float* out = (float*)d_out;

    // workspace layout (~102 MB)
    char* p = (char*)d_ws;
    int*   deg      = (int*)p;   p += (size_t)n * 4;
    int*   next     = (int*)p;   p += (size_t)n * 4;
    int*   row_ptr  = (int*)p;   p += (size_t)(n + 1) * 4;
    int*   partials = (int*)p;   p += 4096 * 4;
    float* rd       = (float*)p; p += (size_t)n * 4;
    int*   col      = (int*)p;   p += (size_t)E * 4;
    float* ya       = (float*)p; p += (size_t)n * D * 4;
    float* yb       = (float*)p; p += (size_t)n * D * 4;

    hipMemsetAsync(deg, 0, (size_t)n * 4, stream);

    deg_kernel<<<(E + 255) / 256, 256, 0, stream>>>(dst, E, deg);

    int nblk = (n + 1023) / 1024;   // 293 for n=300k (<= 1024 required)
    scan_sum_kernel<<<nblk, 1024, 0, stream>>>(deg, n, partials);
    scan_partials_kernel<<<1, 1024, 0, stream>>>(partials, nblk);
    scan_write_kernel<<<nblk, 1024, 0, stream>>>(deg, n, E, partials, row_ptr, next, rd);

    int span = (n + 7) / 8;
    fill_kernel<<<2048, 256, 0, stream>>>(src, dst, E, span, n, next, col);

    int tot32 = n * D;
    init_kernel<<<(tot32 + 255) / 256, 256, 0, stream>>>(ue, ie, rd, nu * D, tot32, ya, out);

    float* yin = ya;
    float* yout = yb;
    int tot8 = n * 8;
    for (int l = 0; l < 3; ++l) {
        layer_kernel<<<(tot8 + 255) / 256, 256, 0, stream>>>(row_ptr, col, rd, yin, yout, out, n);
        float* t = yin; yin = yout; yout = t;
    }
}

// Round 7
// 659.133 us; speedup vs baseline: 2.0072x; 1.7030x over previous
//
#include <hip/hip_runtime.h>
#include <hip/hip_fp16.h>

// LightGCN forward: 3 propagation layers + layer mean.
//
// Pipeline:
//  1. hist:         global 293-bucket histogram of dst (bucket = 1024-node range)
//  2. scan_buckets: exclusive scan -> qbase/qcur
//  3. msplit:       LDS-staged multisplit of edges into dst-buckets (coalesced
//                   writes of packed u32 = (dst&1023)<<19 | src)
//  4. binfill:      one block per bucket: per-node counts in LDS (-> rd, ird,
//                   row_ptr, replacing deg+scan kernels), then CSR col scatter
//                   confined to the bucket's ~68KB window (one block = one XCD
//                   -> 64B lines assemble in L2 before eviction)
//  5. init:         y0 = rd .* x0  (fp16, 64B per node row)
//  6. layer x3:     y_next[i] = rd[i]^2 * sum_{src in row i} y[src]
//                   (gather = one 64B line per edge; no acc traffic)
//  7. merge:        out = 0.25*(x0 + (y1+y2+y3)*sqrt(deg))   [x_l = y_l * ird]

#define D 32
#define TILE 8192
#define MAXB 512

// ---------- 1. bucket histogram ----------
__global__ void hist_kernel(const int* __restrict__ dst, int E, int nb,
                            int* __restrict__ bcnt) {
    __shared__ int h[MAXB];
    int t = threadIdx.x;
    for (int i = t; i < nb; i += blockDim.x) h[i] = 0;
    __syncthreads();
    for (int i = blockIdx.x * blockDim.x + t; i < E; i += gridDim.x * blockDim.x)
        atomicAdd(&h[dst[i] >> 10], 1);
    __syncthreads();
    for (int i = t; i < nb; i += blockDim.x)
        if (h[i]) atomicAdd(&bcnt[i], h[i]);
}

// ---------- 2. scan bucket counts -> qbase (exclusive) + qcur copy ----------
__global__ void scan_buckets_kernel(const int* __restrict__ bcnt, int nb, int E, int n,
                                    int* __restrict__ qbase, int* __restrict__ qcur,
                                    int* __restrict__ row_ptr) {
    __shared__ int sc[1024];
    int t = threadIdx.x;  // 512 threads
    int v0 = (t < nb) ? bcnt[t] : 0;
    int v1 = (t + 512 < nb) ? bcnt[t + 512] : 0;
    sc[t] = v0; sc[t + 512] = v1;
    __syncthreads();
    for (int o = 1; o < 1024; o <<= 1) {
        int a0 = (t >= o) ? sc[t - o] : 0;
        int a1 = (t + 512 >= o) ? sc[t + 512 - o] : 0;
        __syncthreads();
        sc[t] += a0; sc[t + 512] += a1;
        __syncthreads();
    }
    if (t < nb)       { qbase[t]       = sc[t] - v0;       qcur[t]       = sc[t] - v0; }
    if (t + 512 < nb) { qbase[t + 512] = sc[t + 512] - v1; qcur[t + 512] = sc[t + 512] - v1; }
    if (t == 0) { qbase[nb] = E; row_ptr[n] = E; }
}

// ---------- 3. LDS-staged multisplit ----------
__global__ void __launch_bounds__(256)
msplit_kernel(const int* __restrict__ src, const int* __restrict__ dst, int E, int nb,
              int* __restrict__ qcur, unsigned* __restrict__ packed) {
    __shared__ unsigned buf[TILE];
    __shared__ int hist[MAXB], exc[MAXB], gbase[MAXB], off[MAXB], sc[MAXB];
    int t = threadIdx.x;
    int tile0 = blockIdx.x * TILE;
    if (tile0 >= E) return;
    int cnt = min(TILE, E - tile0);

    for (int i = t; i < MAXB; i += 256) hist[i] = 0;
    __syncthreads();
    for (int i = t; i < cnt; i += 256)
        atomicAdd(&hist[dst[tile0 + i] >> 10], 1);
    __syncthreads();

    // inclusive scan of hist[0..MAXB) with 256 threads (2 elems each)
    int h0 = hist[t], h1 = hist[t + 256];
    sc[t] = h0; sc[t + 256] = h1;
    __syncthreads();
    for (int o = 1; o < MAXB; o <<= 1) {
        int a0 = (t >= o) ? sc[t - o] : 0;
        int a1 = (t + 256 >= o) ? sc[t + 256 - o] : 0;
        __syncthreads();
        sc[t] += a0; sc[t + 256] += a1;
        __syncthreads();
    }
    exc[t] = sc[t] - h0;
    exc[t + 256] = sc[t + 256] - h1;
    gbase[t]       = (h0 > 0) ? atomicAdd(&qcur[t], h0)       : 0;
    gbase[t + 256] = (h1 > 0) ? atomicAdd(&qcur[t + 256], h1) : 0;
    off[t] = exc[t];
    off[t + 256] = exc[t + 256];
    __syncthreads();

    // place into LDS buffer grouped by bucket
    for (int i = t; i < cnt; i += 256) {
        int d = dst[tile0 + i];              // L2-warm re-read
        int s = src[tile0 + i];
        int b = d >> 10;
        int pos = atomicAdd(&off[b], 1);
        buf[pos] = ((unsigned)(d & 1023) << 19) | (unsigned)s;
    }
    __syncthreads();

    // copy out: contiguous per-bucket segments -> coalesced global writes
    for (int i = t; i < cnt; i += 256) {
        int lo = 0, hi = nb - 1;             // largest b with exc[b] <= i
        while (lo < hi) { int mid = (lo + hi + 1) >> 1; if (exc[mid] <= i) lo = mid; else hi = mid - 1; }
        packed[gbase[lo] + (i - exc[lo])] = buf[i];
    }
}

// ---------- 4. per-bucket CSR fill + node stats ----------
__global__ void __launch_bounds__(256)
binfill_kernel(const unsigned* __restrict__ packed, const int* __restrict__ qbase,
               int nb, int n, float* __restrict__ rd, float* __restrict__ ird,
               int* __restrict__ row_ptr, int* __restrict__ col) {
    int b = blockIdx.x;
    int lo = b << 10;
    int nn = min(1024, n - lo);
    int e0 = qbase[b], e1 = qbase[b + 1];
    __shared__ int cnt[1024], exc[1024], nxt[1024];
    __shared__ int wsum[256];
    int t = threadIdx.x;
    for (int i = t; i < 1024; i += 256) { cnt[i] = 0; nxt[i] = 0; }
    __syncthreads();
    for (int i = e0 + t; i < e1; i += 256)
        atomicAdd(&cnt[packed[i] >> 19], 1);
    __syncthreads();
    // exclusive scan of cnt[0..1024): 4 elems/thread + LDS scan of thread sums
    int l0 = cnt[4*t], l1 = cnt[4*t+1], l2 = cnt[4*t+2], l3 = cnt[4*t+3];
    int s01 = l0 + l1;
    wsum[t] = s01 + l2 + l3;
    __syncthreads();
    for (int o = 1; o < 256; o <<= 1) {
        int a = (t >= o) ? wsum[t - o] : 0;
        __syncthreads();
        wsum[t] += a;
        __syncthreads();
    }
    int pre = (t > 0) ? wsum[t - 1] : 0;
    exc[4*t]   = pre;
    exc[4*t+1] = pre + l0;
    exc[4*t+2] = pre + s01;
    exc[4*t+3] = pre + s01 + l2;
    __syncthreads();
    for (int i = t; i < nn; i += 256) {
        int c = cnt[i];
        row_ptr[lo + i] = e0 + exc[i];
        rd[lo + i]  = (c > 0) ? rsqrtf((float)c) : 0.0f;
        ird[lo + i] = (c > 0) ? sqrtf((float)c)  : 0.0f;   // = 1/rd (0 if deg 0)
    }
    // scatter col within this bucket's window (~68KB): single block -> lines
    // assemble in this XCD's L2 before eviction
    for (int i = e0 + t; i < e1; i += 256) {
        unsigned pk = packed[i];
        int dlo = pk >> 19;
        int p = atomicAdd(&nxt[dlo], 1);
        col[e0 + exc[dlo] + p] = (int)(pk & 0x7FFFF);
    }
}

// ---------- 5. init y0 = rd .* x0 (fp16) ----------
__global__ void init_kernel(const float* __restrict__ ue, const float* __restrict__ ie,
                            const float* __restrict__ rd, int nu32, int tot32,
                            __half* __restrict__ y0) {
    int gid = blockIdx.x * blockDim.x + threadIdx.x;
    int i2 = gid * 2;
    if (i2 < tot32) {
        float v0 = (i2 < nu32) ? ue[i2] : ie[i2 - nu32];
        float v1 = (i2 < nu32) ? ue[i2 + 1] : ie[i2 + 1 - nu32];   // nu32 even
        float r = rd[i2 >> 5];
        *reinterpret_cast<__half2*>(y0 + i2) = __floats2half2_rn(r * v0, r * v1);
    }
}

// ---------- 6. propagation layer ----------
// 8-lane group per node; lane q holds halves [4q, 4q+4) (8B) of the 64B row.
__global__ void layer_kernel(const int* __restrict__ row_ptr, const int* __restrict__ col,
                             const float* __restrict__ rd, const __half* __restrict__ yin,
                             __half* __restrict__ yout, int n) {
    int gid = blockIdx.x * blockDim.x + threadIdx.x;
    int node = gid >> 3;
    int q = gid & 7;
    if (node >= n) return;
    int e0 = row_ptr[node];
    int e1 = row_ptr[node + 1];
    float4 s = make_float4(0.f, 0.f, 0.f, 0.f);
    for (int base = e0; base < e1; base += 8) {
        int idx = base + q;
        int c = (idx < e1) ? col[idx] : 0;
        int m = min(8, e1 - base);
        for (int j = 0; j < m; ++j) {
            int cj = __shfl(c, j, 8);
            uint2 u = *reinterpret_cast<const uint2*>(yin + cj * D + q * 4);
            float2 f0 = __half22float2(*reinterpret_cast<__half2*>(&u.x));
            float2 f1 = __half22float2(*reinterpret_cast<__half2*>(&u.y));
            s.x += f0.x; s.y += f0.y; s.z += f1.x; s.w += f1.y;
        }
    }
    float r = rd[node];
    float r2 = r * r;                 // y_next = rd^2 * sum
    __half2 o0 = __floats2half2_rn(r2 * s.x, r2 * s.y);
    __half2 o1 = __floats2half2_rn(r2 * s.z, r2 * s.w);
    uint2 o;
    o.x = *reinterpret_cast<unsigned*>(&o0);
    o.y = *reinterpret_cast<unsigned*>(&o1);
    *reinterpret_cast<uint2*>(yout + node * D + q * 4) = o;
}

// ---------- 7. merge: out = 0.25*(x0 + (y1+y2+y3)*ird) ----------
__global__ void merge_kernel(const float* __restrict__ ue, const float* __restrict__ ie,
                             const float* __restrict__ ird,
                             const __half* __restrict__ y1, const __half* __restrict__ y2,
                             const __half* __restrict__ y3,
                             int nu32, int tot32, float* __restrict__ out) {
    int gid = blockIdx.x * blockDim.x + threadIdx.x;
    int i2 = gid * 2;
    if (i2 < tot32) {
        float v0 = (i2 < nu32) ? ue[i2] : ie[i2 - nu32];
        float v1 = (i2 < nu32) ? ue[i2 + 1] : ie[i2 + 1 - nu32];
        float iv = ird[i2 >> 5];
        float2 a = __half22float2(*reinterpret_cast<const __half2*>(y1 + i2));
        float2 b = __half22float2(*reinterpret_cast<const __half2*>(y2 + i2));
        float2 c = __half22float2(*reinterpret_cast<const __half2*>(y3 + i2));
        float o0 = 0.25f * (v0 + (a.x + b.x + c.x) * iv);
        float o1 = 0.25f * (v1 + (a.y + b.y + c.y) * iv);
        *reinterpret_cast<float2*>(out + i2) = make_float2(o0, o1);
    }
}

extern "C" void kernel_launch(void* const* d_in, const int* in_sizes, int n_in,
                              void* d_out, int out_size, void* d_ws, size_t ws_size,
                              hipStream_t stream) {
    const int*   edge = (const int*)d_in[0];
    const float* ue   = (const float*)d_in[3];
    const float* ie   = (const float*)d_in[4];
    int E  = in_sizes[0] / 2;
    int nu = in_sizes[3] / D;
    int ni = in_sizes[4] / D;
    int n  = nu + ni;
    int nb = (n + 1023) >> 10;      // 293 buckets (must be <= MAXB)
    const int* src = edge;
    const int* dst = edge + E;
    float* out = (float*)d_out;

    // workspace layout (~101 MB)
    char* p = (char*)d_ws;
    int*      bcnt    = (int*)p;      p += (MAXB + 1) * 4;
    int*      qbase   = (int*)p;      p += (MAXB + 1) * 4;
    int*      qcur    = (int*)p;      p += (MAXB + 1) * 4;
    int*      row_ptr = (int*)p;      p += (size_t)(n + 1) * 4;
    float*    rd      = (float*)p;    p += (size_t)n * 4;
    float*    ird     = (float*)p;    p += (size_t)n * 4;
    unsigned* packed  = (unsigned*)p; p += (size_t)E * 4;
    int*      col     = (int*)p;      p += (size_t)E * 4;
    __half*   yA      = (__half*)p;   p += (size_t)n * D * 2;
    __half*   yB      = (__half*)p;   p += (size_t)n * D * 2;
    __half*   yC      = (__half*)p;   p += (size_t)n * D * 2;

    hipMemsetAsync(bcnt, 0, (MAXB + 1) * 4, stream);

    hist_kernel<<<1024, 256, 0, stream>>>(dst, E, nb, bcnt);
    scan_buckets_kernel<<<1, 512, 0, stream>>>(bcnt, nb, E, n, qbase, qcur, row_ptr);
    msplit_kernel<<<(E + TILE - 1) / TILE, 256, 0, stream>>>(src, dst, E, nb, qcur, packed);
    binfill_kernel<<<nb, 256, 0, stream>>>(packed, qbase, nb, n, rd, ird, row_ptr, col);

    int tot32 = n * D;
    init_kernel<<<(n * 16 + 255) / 256, 256, 0, stream>>>(ue, ie, rd, nu * D, tot32, yA);

    int tot8 = n * 8;
    layer_kernel<<<(tot8 + 255) / 256, 256, 0, stream>>>(row_ptr, col, rd, yA, yB, n);  // y1
    layer_kernel<<<(tot8 + 255) / 256, 256, 0, stream>>>(row_ptr, col, rd, yB, yC, n);  // y2
    layer_kernel<<<(tot8 + 255) / 256, 256, 0, stream>>>(row_ptr, col, rd, yC, yA, n);  // y3

    merge_kernel<<<(n * 16 + 255) / 256, 256, 0, stream>>>(ue, ie, ird, yB, yC, yA,
                                                           nu * D, tot32, out);
}